// Round 9
// baseline (219.507 us; speedup 1.0000x reference)
//
#include <hip/hip_runtime.h>
#include <cstdint>
#include <cstddef>

// ---------------------------------------------------------------------------
// MHA bf16-MFMA pipeline, round 9.
//   prep:       Wo cast + LDS-tiled W_{q,k,v} transpose
//   gemm_proj:  batched 3x proj, f32 A cast in staging, XCD swizzle (R8) +
//               NEW distance-2 ping-pong reg prefetch (write 1-iter-old regs
//               at iter top -> no load->ds_write stall at the barrier)
//   flash:      K*Q^T, no-max softmax, frag-major LDS, 32 q/wave, dist-2
//   gemm_out:   NEW 128x128 tile, 512 thr, 256 blocks (1/CU), A-colocating
//               swizzle, dist-2 staging; 16 MFMA per wave-iter at 32B/thread
// ---------------------------------------------------------------------------

typedef unsigned short bf16_t;
typedef __attribute__((ext_vector_type(8))) short short8;   // MFMA A/B frag (8 bf16)
typedef __attribute__((ext_vector_type(4))) float f32x4;    // MFMA C/D frag

__device__ __forceinline__ uint32_t fbits(float f) {
  union { float f; uint32_t u; } v; v.f = f; return v.u;
}
__device__ __forceinline__ bf16_t f2bf(float f) {          // RNE
  uint32_t u = fbits(f);
  return (bf16_t)((u + 0x7FFFu + ((u >> 16) & 1u)) >> 16);
}
// pack 2 floats -> 2 bf16 (round-half-up): 2 adds + 1 v_perm
__device__ __forceinline__ uint32_t packbf2(float lo, float hi) {
  uint32_t a = fbits(hi) + 0x8000u;
  uint32_t b = fbits(lo) + 0x8000u;
  return __builtin_amdgcn_perm(a, b, 0x07060302u);         // {a.hi16, b.hi16}
}
__device__ __forceinline__ int4 cvt8(f32x4 lo, f32x4 hi) { // 8 f32 -> 8 bf16
  return make_int4((int)packbf2(lo.x, lo.y), (int)packbf2(lo.z, lo.w),
                   (int)packbf2(hi.x, hi.y), (int)packbf2(hi.z, hi.w));
}

// ---- prep: Wo cast + tiled transpose of W_{q,k,v} --------------------------
__global__ void prep_kernel(const float* __restrict__ Wo,
                            const float* __restrict__ Wq, const float* __restrict__ Wk,
                            const float* __restrict__ Wv,
                            bf16_t* __restrict__ Woo,
                            bf16_t* __restrict__ Wtq, bf16_t* __restrict__ Wtk,
                            bf16_t* __restrict__ Wtv) {
  int blk = blockIdx.x;
  int tid = threadIdx.x;
  if (blk < 1024) {                          // Wo f32 -> bf16 (1M elems)
    int i = blk * 256 + tid;
    f32x4 val = ((const f32x4*)Wo)[i];
    ushort4 o;
    o.x = f2bf(val.x); o.y = f2bf(val.y); o.z = f2bf(val.z); o.w = f2bf(val.w);
    ((ushort4*)Woo)[i] = o;
  } else {
    // W[16,1024,64] -> Wt[h*64+dk][d], tile = one head x 32 d-rows
    int blk2 = blk - 1024;                   // [0, 1536)
    int z = blk2 >> 9, t = blk2 & 511;       // 3 x 512
    const float* W = z == 0 ? Wq : z == 1 ? Wk : Wv;
    bf16_t* Wt = z == 0 ? Wtq : z == 1 ? Wtk : Wtv;
    int h = t >> 5, d0 = (t & 31) * 32;
    __shared__ float tile[32][65];
    const float* src = W + ((size_t)h << 16) + (size_t)d0 * 64;
    int d = tid >> 3;
#pragma unroll
    for (int j = 0; j < 2; j++) {
      int dk = (tid & 7) * 8 + j * 4;
      *(f32x4*)&tile[d][dk] = *(const f32x4*)(src + d * 64 + dk);
    }
    __syncthreads();
    int dk2 = tid >> 2, c = tid & 3;
    union { ushort s[8]; int4 v; } o;
#pragma unroll
    for (int j = 0; j < 8; j++) o.s[j] = f2bf(tile[c * 8 + j][dk2]);
    *(int4*)(Wt + (size_t)(h * 64 + dk2) * 1024 + d0 + c * 8) = o.v;
  }
}

// ---- batched projection GEMM: f32 A cast in staging, XCD swizzle, dist-2 ---
// bid -> nIdx = bid/96, g = bid%96 (m,z). 96 % 8 == 0 => all 8 nIdx blocks of
// a group share XCD g%8 -> A-tile L2-resident after first fetch.
__global__ __launch_bounds__(256) void gemm_proj_kernel(
    const float* __restrict__ A0, const float* __restrict__ A1, const float* __restrict__ A2,
    const bf16_t* __restrict__ B0, const bf16_t* __restrict__ B1, const bf16_t* __restrict__ B2,
    bf16_t* __restrict__ O0, bf16_t* __restrict__ O1, bf16_t* __restrict__ O2,
    float s0)
{
  const int bid = blockIdx.x;
  const int nIdx = bid / 96;
  const int g = bid - nIdx * 96;
  const int z = g % 3;
  const int m0 = (g / 3) * 128, n0 = nIdx * 128;

  const float* A   = z == 0 ? A0 : z == 1 ? A1 : A2;
  const bf16_t* Bt = z == 0 ? B0 : z == 1 ? B1 : B2;
  bf16_t* Cout     = z == 0 ? O0 : z == 1 ? O1 : O2;
  const float scale = z == 0 ? s0 : 1.0f;
  const int K = 1024;

  __shared__ alignas(16) bf16_t smem[18432];

  const int tid = threadIdx.x;
  const int lane = tid & 63, wave = tid >> 6;
  const int wm = wave >> 1, wn = wave & 1;
  const int quad = lane >> 4, l15 = lane & 15;

  f32x4 acc[4][4];
#pragma unroll
  for (int i = 0; i < 4; i++)
#pragma unroll
    for (int j = 0; j < 4; j++) acc[i][j] = (f32x4)0.0f;

  const int c0 = wave * 128 + lane;       // 16B-bf16 chunk ids (4 per 32-el row)
  const int c1 = c0 + 64;
  const float*  pa0 = A  + (size_t)(m0 + (c0 >> 2)) * K + (c0 & 3) * 8;
  const float*  pa1 = A  + (size_t)(m0 + (c1 >> 2)) * K + (c1 & 3) * 8;
  const bf16_t* pb0 = Bt + (size_t)(n0 + (c0 >> 2)) * K + (c0 & 3) * 8;
  const bf16_t* pb1 = Bt + (size_t)(n0 + (c1 >> 2)) * K + (c1 & 3) * 8;
  const int s0a = c0 * 8, s1a = c1 * 8;

  auto compute = [&](int co) {
    short8 af[4], bfr[4];
#pragma unroll
    for (int mi = 0; mi < 4; mi++)
      af[mi] = *(const short8*)(smem + co + (wm * 64 + mi * 16 + l15) * 32 + quad * 8);
#pragma unroll
    for (int ni = 0; ni < 4; ni++)
      bfr[ni] = *(const short8*)(smem + co + 4096 + (wn * 64 + ni * 16 + l15) * 32 + quad * 8);
#pragma unroll
    for (int mi = 0; mi < 4; mi++)
#pragma unroll
      for (int ni = 0; ni < 4; ni++)
        acc[mi][ni] = __builtin_amdgcn_mfma_f32_16x16x32_bf16(af[mi], bfr[ni], acc[mi][ni], 0, 0, 0);
  };

  // prologue: tile0 -> buf0 directly; tile1 -> reg set A
  {
    f32x4 t0l = *(const f32x4*)pa0, t0h = *(const f32x4*)(pa0 + 4);
    f32x4 t1l = *(const f32x4*)pa1, t1h = *(const f32x4*)(pa1 + 4);
    *(int4*)(smem + s0a) = cvt8(t0l, t0h);
    *(int4*)(smem + s1a) = cvt8(t1l, t1h);
    *(int4*)(smem + 4096 + s0a) = *(const int4*)pb0;
    *(int4*)(smem + 4096 + s1a) = *(const int4*)pb1;
  }
  f32x4 aA0l = *(const f32x4*)(pa0 + 32), aA0h = *(const f32x4*)(pa0 + 36);
  f32x4 aA1l = *(const f32x4*)(pa1 + 32), aA1h = *(const f32x4*)(pa1 + 36);
  int4  bA0  = *(const int4*)(pb0 + 32);
  int4  bA1  = *(const int4*)(pb1 + 32);
  __syncthreads();

  f32x4 aB0l, aB0h, aB1l, aB1h; int4 bB0, bB1;
  for (int it = 0; it < 32; it += 2) {
    // even iter: compute buf0; write set A (tile it+1) -> buf1; load it+2
    *(int4*)(smem + 8192 + s0a) = cvt8(aA0l, aA0h);
    *(int4*)(smem + 8192 + s1a) = cvt8(aA1l, aA1h);
    *(int4*)(smem + 8192 + 4096 + s0a) = bA0;
    *(int4*)(smem + 8192 + 4096 + s1a) = bA1;
    if (it + 2 < 32) {
      const int ko = (it + 2) * 32;
      aB0l = *(const f32x4*)(pa0 + ko); aB0h = *(const f32x4*)(pa0 + ko + 4);
      aB1l = *(const f32x4*)(pa1 + ko); aB1h = *(const f32x4*)(pa1 + ko + 4);
      bB0 = *(const int4*)(pb0 + ko);
      bB1 = *(const int4*)(pb1 + ko);
    }
    compute(0);
    __syncthreads();

    // odd iter: compute buf1; write set B (tile it+2) -> buf0; load it+3
    if (it + 2 < 32) {
      *(int4*)(smem + s0a) = cvt8(aB0l, aB0h);
      *(int4*)(smem + s1a) = cvt8(aB1l, aB1h);
      *(int4*)(smem + 4096 + s0a) = bB0;
      *(int4*)(smem + 4096 + s1a) = bB1;
    }
    if (it + 3 < 32) {
      const int ko = (it + 3) * 32;
      aA0l = *(const f32x4*)(pa0 + ko); aA0h = *(const f32x4*)(pa0 + ko + 4);
      aA1l = *(const f32x4*)(pa1 + ko); aA1h = *(const f32x4*)(pa1 + ko + 4);
      bA0 = *(const int4*)(pb0 + ko);
      bA1 = *(const int4*)(pb1 + ko);
    }
    compute(8192);
    __syncthreads();
  }

  const int s0r = m0 & 2047, bb = m0 >> 11, hp = n0 >> 6;
  if (z < 2) {
    bf16_t* slot = smem + wn * 9216;
#pragma unroll
    for (int ni = 0; ni < 4; ni++)
#pragma unroll
      for (int mi = 0; mi < 4; mi++)
#pragma unroll
        for (int r = 0; r < 4; r++)
          slot[(wm * 64 + mi * 16 + quad * 4 + r) * 72 + ni * 16 + l15] =
              f2bf(acc[mi][ni][r] * scale);
    __syncthreads();
#pragma unroll
    for (int rd = 0; rd < 8; ++rd) {
      int idx = rd * 256 + tid;
      int si = idx >> 10, mm = (idx >> 3) & 127, c8 = idx & 7;
      int4 val = *(const int4*)(smem + si * 9216 + mm * 72 + c8 * 8);
      *(int4*)(Cout + ((size_t)((bb * 16 + hp + si) * 2048 + s0r + mm)) * 64 + c8 * 8) = val;
    }
  } else {
    bf16_t* slot = smem + wn * 8704;
#pragma unroll
    for (int ni = 0; ni < 4; ni++)
#pragma unroll
      for (int mi = 0; mi < 4; mi++) {
        uint2 pk = make_uint2(packbf2(acc[mi][ni][0], acc[mi][ni][1]),
                              packbf2(acc[mi][ni][2], acc[mi][ni][3]));
        *(uint2*)(slot + (ni * 16 + l15) * 136 + wm * 64 + mi * 16 + quad * 4) = pk;
      }
    __syncthreads();
#pragma unroll
    for (int rd = 0; rd < 8; ++rd) {
      int idx = rd * 256 + tid;
      int si = idx >> 10, c = (idx >> 4) & 63, ck = idx & 15;
      int4 val = *(const int4*)(smem + si * 8704 + c * 136 + ck * 8);
      *(int4*)(Cout + (size_t)(bb * 16 + hp + si) * 131072 + (size_t)c * 2048 + s0r + ck * 8) = val;
    }
  }
}

// ---- final GEMM: 128x128 tile, 512 threads, 256 blocks (1/CU), dist-2 ------
// bid: n0 = (bid>>5)*128, m0 = (bid&31)*128; 32 % 8 == 0 => the 8 n-blocks
// sharing a ctx A-tile land on XCD m%8.
__global__ __launch_bounds__(512) void gemm_out_kernel(
    const bf16_t* __restrict__ A, const bf16_t* __restrict__ Bt,
    float* __restrict__ C, const float* __restrict__ bias)
{
  const int K = 1024, N = 1024;
  __shared__ alignas(16) bf16_t smem[16384];   // 2 x (A 4096 + B 4096)
  const int tid = threadIdx.x;
  const int lane = tid & 63, wave = tid >> 6;
  const int wm = wave >> 1, wn = wave & 1;     // 4 x 2 wave grid
  const int quad = lane >> 4, l15 = lane & 15;
  const int m0 = (blockIdx.x & 31) * 128, n0 = (blockIdx.x >> 5) * 128;

  f32x4 acc[2][4];
#pragma unroll
  for (int i = 0; i < 2; i++)
#pragma unroll
    for (int j = 0; j < 4; j++) acc[i][j] = (f32x4)0.0f;

  const int ca = tid;                          // 512 A chunks: row=ca>>2, ch=ca&3
  const int cb = tid;                          // 512 B chunks
  const bf16_t* pa = A  + (size_t)(m0 + (ca >> 2)) * K + (ca & 3) * 8;
  const bf16_t* pb = Bt + (size_t)(n0 + (cb >> 2)) * K + (cb & 3) * 8;
  const int sa = ca * 8, sb = 4096 + cb * 8;

  auto compute = [&](int co) {
    short8 af[2], bfr[4];
#pragma unroll
    for (int mi = 0; mi < 2; mi++)
      af[mi] = *(const short8*)(smem + co + (wm * 32 + mi * 16 + l15) * 32 + quad * 8);
#pragma unroll
    for (int ni = 0; ni < 4; ni++)
      bfr[ni] = *(const short8*)(smem + co + 4096 + (wn * 64 + ni * 16 + l15) * 32 + quad * 8);
#pragma unroll
    for (int mi = 0; mi < 2; mi++)
#pragma unroll
      for (int ni = 0; ni < 4; ni++)
        acc[mi][ni] = __builtin_amdgcn_mfma_f32_16x16x32_bf16(af[mi], bfr[ni], acc[mi][ni], 0, 0, 0);
  };

  // prologue: tile0 -> buf0; tile1 -> reg set A
  *(int4*)(smem + sa) = *(const int4*)pa;
  *(int4*)(smem + sb) = *(const int4*)pb;
  int4 rAa = *(const int4*)(pa + 32);
  int4 rAb = *(const int4*)(pb + 32);
  __syncthreads();

  int4 rBa, rBb;
  for (int it = 0; it < 32; it += 2) {
    *(int4*)(smem + 8192 + sa) = rAa;
    *(int4*)(smem + 8192 + sb) = rAb;
    if (it + 2 < 32) {
      const int ko = (it + 2) * 32;
      rBa = *(const int4*)(pa + ko);
      rBb = *(const int4*)(pb + ko);
    }
    compute(0);
    __syncthreads();

    if (it + 2 < 32) {
      *(int4*)(smem + sa) = rBa;
      *(int4*)(smem + sb) = rBb;
    }
    if (it + 3 < 32) {
      const int ko = (it + 3) * 32;
      rAa = *(const int4*)(pa + ko);
      rAb = *(const int4*)(pb + ko);
    }
    compute(8192);
    __syncthreads();
  }

#pragma unroll
  for (int ni = 0; ni < 4; ni++) {
    int col = n0 + wn * 64 + ni * 16 + l15;
    float bv = bias[col];
#pragma unroll
    for (int mi = 0; mi < 2; mi++) {
      int row = m0 + wm * 32 + mi * 16 + quad * 4;
#pragma unroll
      for (int r = 0; r < 4; r++)
        C[(size_t)(row + r) * N + col] = acc[mi][ni][r] + bv;
    }
  }
}

// ---- flash attention: 32 q/wave, distance-2 prefetch, early staging --------
__global__ __launch_bounds__(512) void flash_kernel(
    const bf16_t* __restrict__ qh, const bf16_t* __restrict__ kh,
    const bf16_t* __restrict__ vT, bf16_t* __restrict__ ctx)
{
  __shared__ alignas(16) bf16_t KtF[2][4096];
  __shared__ alignas(16) bf16_t VtF[2][4096];
  __shared__ alignas(16) bf16_t PtF[16384];           // 8 waves x 2048 elems
  const int tid = threadIdx.x, lane = tid & 63, wave = tid >> 6;
  const int quad = lane >> 4, l15 = lane & 15;
  const int q0 = blockIdx.x * 256;
  const int h = blockIdx.y, b = blockIdx.z;
  const size_t headoff = (size_t)(b * 16 + h) * 2048 * 64;
  const bf16_t* Q = qh + headoff;
  const bf16_t* K = kh + headoff;
  const bf16_t* V = vT + headoff;                     // [64][2048]

  short8 qf[2][2];
#pragma unroll
  for (int g = 0; g < 2; g++)
#pragma unroll
    for (int ks = 0; ks < 2; ks++)
      qf[g][ks] = *(const short8*)(Q + (size_t)(q0 + wave * 32 + g * 16 + l15) * 64
                                   + ks * 32 + quad * 8);

  f32x4 O[2][4];
#pragma unroll
  for (int g = 0; g < 2; g++)
#pragma unroll
    for (int mi = 0; mi < 4; mi++) O[g][mi] = (f32x4)0.0f;
  f32x4 lacc[2] = {(f32x4)0.0f, (f32x4)0.0f};

  const bf16_t* Kp = K + (size_t)((wave >> 1) * 16 + l15) * 64 + (wave & 1) * 32 + quad * 8;
  const bf16_t* Vp = V + (size_t)((wave >> 1) * 16 + l15) * 2048 + (wave & 1) * 32 + quad * 8;
  const int soff = wave * 512 + lane * 8;             // frag-major staging slot
  const int pwb = wave * 4096 + ((quad >> 1) * 16 + l15) * 16 + 8 * (quad & 1);

  auto body = [&](int buf) {
    f32x4 S[2][4];
#pragma unroll
    for (int g = 0; g < 2; g++)
#pragma unroll
      for (int mi = 0; mi < 4; mi++) S[g][mi] = (f32x4)0.0f;
#pragma unroll
    for (int ks = 0; ks < 2; ks++) {
#pragma unroll
      for (int mi = 0; mi < 4; mi++) {
        short8 kf = *(const short8*)(&KtF[buf][(mi * 2 + ks) * 512 + lane * 8]);
        S[0][mi] = __builtin_amdgcn_mfma_f32_16x16x32_bf16(kf, qf[0][ks], S[0][mi], 0, 0, 0);
        S[1][mi] = __builtin_amdgcn_mfma_f32_16x16x32_bf16(kf, qf[1][ks], S[1][mi], 0, 0, 0);
      }
    }
#pragma unroll
    for (int g = 0; g < 2; g++) {
#pragma unroll
      for (int mi = 0; mi < 4; mi++)
#pragma unroll
        for (int r = 0; r < 4; r++)
          S[g][mi][r] = __builtin_amdgcn_exp2f(S[g][mi][r]);
      lacc[g] += (S[g][0] + S[g][1]) + (S[g][2] + S[g][3]);
    }
#pragma unroll
    for (int g = 0; g < 2; g++)
#pragma unroll
      for (int mi = 0; mi < 4; mi++) {
        uint2 pk = make_uint2(packbf2(S[g][mi][0], S[g][mi][1]),
                              packbf2(S[g][mi][2], S[g][mi][3]));
        *(uint2*)((char*)PtF + pwb + g * 2048 + (mi >> 1) * 1024 + (mi & 1) * 512) = pk;
      }
#pragma unroll
    for (int ks = 0; ks < 2; ks++) {
      short8 pf0 = *(const short8*)(&PtF[wave * 2048 + (ks * 64 + lane) * 8]);
      short8 pf1 = *(const short8*)(&PtF[wave * 2048 + 1024 + (ks * 64 + lane) * 8]);
#pragma unroll
      for (int mi = 0; mi < 4; mi++) {
        short8 vf = *(const short8*)(&VtF[buf][(mi * 2 + ks) * 512 + lane * 8]);
        O[0][mi] = __builtin_amdgcn_mfma_f32_16x16x32_bf16(vf, pf0, O[0][mi], 0, 0, 0);
        O[1][mi] = __builtin_amdgcn_mfma_f32_16x16x32_bf16(vf, pf1, O[1][mi], 0, 0, 0);
      }
    }
  };

  // prologue: tile0 -> buf0; tile1 -> regsA
  int4 k0 = *(const int4*)Kp, v0 = *(const int4*)Vp;
  *(int4*)(&KtF[0][soff]) = k0;
  *(int4*)(&VtF[0][soff]) = v0;
  int4 kA = *(const int4*)(Kp + 4096), vA = *(const int4*)(Vp + 64);
  __syncthreads();

  for (int it = 0; it < 32; it += 2) {
    *(int4*)(&KtF[1][soff]) = kA;
    *(int4*)(&VtF[1][soff]) = vA;
    int4 kB, vB;
    if (it + 2 < 32) {
      kB = *(const int4*)(Kp + (size_t)(it + 2) * 4096);
      vB = *(const int4*)(Vp + (size_t)(it + 2) * 64);
    }
    body(0);
    __syncthreads();

    if (it + 2 < 32) {
      *(int4*)(&KtF[0][soff]) = kB;
      *(int4*)(&VtF[0][soff]) = vB;
    }
    if (it + 3 < 32) {
      kA = *(const int4*)(Kp + (size_t)(it + 3) * 4096);
      vA = *(const int4*)(Vp + (size_t)(it + 3) * 64);
    }
    body(1);
    __syncthreads();
  }

#pragma unroll
  for (int g = 0; g < 2; g++) {
    float l = (lacc[g][0] + lacc[g][1]) + (lacc[g][2] + lacc[g][3]);
    l += __shfl_xor(l, 16, 64);
    l += __shfl_xor(l, 32, 64);
    float inv = 1.0f / l;
    int qrow = q0 + wave * 32 + g * 16 + l15;
    bf16_t* crow = ctx + ((size_t)(b * 2048 + qrow)) * 1024 + h * 64;
#pragma unroll
    for (int mi = 0; mi < 4; mi++) {
      uint2 pk = make_uint2(packbf2(O[g][mi][0] * inv, O[g][mi][1] * inv),
                            packbf2(O[g][mi][2] * inv, O[g][mi][3] * inv));
      *(uint2*)(crow + mi * 16 + quad * 4) = pk;
    }
  }
}

// ---------------------------------------------------------------------------
extern "C" void kernel_launch(void* const* d_in, const int* in_sizes, int n_in,
                              void* d_out, int out_size, void* d_ws, size_t ws_size,
                              hipStream_t stream)
{
  const float* q  = (const float*)d_in[0];
  const float* k  = (const float*)d_in[1];
  const float* v  = (const float*)d_in[2];
  const float* Wq = (const float*)d_in[3];
  const float* Wk = (const float*)d_in[4];
  const float* Wv = (const float*)d_in[5];
  const float* Wo = (const float*)d_in[6];
  const float* bo = (const float*)d_in[7];
  float* out = (float*)d_out;

  const size_t NX = (size_t)4096 * 1024;
  const size_t NW = (size_t)1024 * 1024;

  char* p = (char*)d_ws;
  bf16_t* Wtq = (bf16_t*)p; p += NW * 2;
  bf16_t* Wtk = (bf16_t*)p; p += NW * 2;
  bf16_t* Wtv = (bf16_t*)p; p += NW * 2;
  bf16_t* Wob = (bf16_t*)p; p += NW * 2;
  bf16_t* qhb = (bf16_t*)p; p += NX * 2;
  bf16_t* khb = (bf16_t*)p; p += NX * 2;
  bf16_t* vTb = (bf16_t*)p; p += NX * 2;
  bf16_t* ctxb = (bf16_t*)p; p += NX * 2;

  prep_kernel<<<2560, 256, 0, stream>>>(Wo, Wq, Wk, Wv, Wob, Wtq, Wtk, Wtv);

  const float qscale = 0.125f * 1.44269504088896340736f;   // 1/sqrt(64) * log2(e)
  gemm_proj_kernel<<<768, 256, 0, stream>>>(q, k, v, Wtq, Wtk, Wtv,
                                            qhb, khb, vTb, qscale);

  flash_kernel<<<dim3(8, 16, 2), 512, 0, stream>>>(qhb, khb, vTb, ctxb);

  gemm_out_kernel<<<256, 512, 0, stream>>>(ctxb, Wob, out, bo);

  (void)in_sizes; (void)n_in; (void)out_size; (void)ws_size;
}